// Round 4
// baseline (75.747 us; speedup 1.0000x reference)
//
#include <hip/hip_runtime.h>
#include <hip/hip_bf16.h>
#include <math.h>

#define N_ROWS 8192
#define D_DIM  256
#define BM 128
#define BN 64
#define JSPLIT 8
#define JRANGE (N_ROWS / JSPLIT)     // 1024
#define NT (JRANGE / BN)             // 16 j-steps per block

typedef __attribute__((ext_vector_type(4))) float f32x4;
typedef __attribute__((ext_vector_type(8))) short bf16x8;

// ---------------- kernel 1: L2-normalize rows, cast to bf16 -----------------
__global__ void norm_cast_kernel(const float* __restrict__ out0,
                                 const float* __restrict__ out1,
                                 __hip_bfloat16* __restrict__ a_bf,
                                 __hip_bfloat16* __restrict__ b_bf) {
    int wave = (blockIdx.x * blockDim.x + threadIdx.x) >> 6;
    int lane = threadIdx.x & 63;
    const float* src        = (wave < N_ROWS) ? out0 : out1;
    __hip_bfloat16* dst     = (wave < N_ROWS) ? a_bf : b_bf;
    int row = (wave < N_ROWS) ? wave : wave - N_ROWS;

    float4 v = *reinterpret_cast<const float4*>(src + (size_t)row * D_DIM + lane * 4);
    float ss = v.x * v.x + v.y * v.y + v.z * v.z + v.w * v.w;
    #pragma unroll
    for (int off = 32; off; off >>= 1) ss += __shfl_xor(ss, off);
    float inv = 1.0f / fmaxf(sqrtf(ss), 1e-12f);

    union { ushort4 u; __hip_bfloat16 h[4]; } o;
    o.h[0] = __float2bfloat16(v.x * inv);
    o.h[1] = __float2bfloat16(v.y * inv);
    o.h[2] = __float2bfloat16(v.z * inv);
    o.h[3] = __float2bfloat16(v.w * inv);
    *reinterpret_cast<ushort4*>(dst + (size_t)row * D_DIM + lane * 4) = o.u;
}

// ------- kernel 2: flash-style fused GEMM + exp + masked row-sums -----------
// 512 blocks = 64 row-tiles x 8 j-splits (one j-split per XCD). 8 waves in a
// 4x2 grid, wave-tile 32x32. A-slice per wave in registers (full K=256,
// 64 VGPR). B double-buffered in LDS (2x32KB -> 2 blocks/CU, 4 waves/SIMD),
// staged via global_load_lds(16B) with 4-bit XOR swizzle:
//   LDS[row][slot] = global[row][slot ^ (row&15)]   (slot = 16B unit, 32/row)
__global__ __launch_bounds__(512, 4)
void fused_flash_kernel(const __hip_bfloat16* __restrict__ A,
                        const __hip_bfloat16* __restrict__ B,
                        const int* __restrict__ labels,
                        float* __restrict__ pos_sum,
                        float* __restrict__ all_sum) {
    __shared__ __hip_bfloat16 Bs[2][BN * D_DIM];   // 2 x 32 KB

    const int tid    = threadIdx.x;
    const int lane   = tid & 63;
    const int wid    = tid >> 6;        // 0..7
    const int wr     = wid >> 1;        // 0..3  (row band of 32)
    const int wc     = wid & 1;         // 0..1  (col half of 32)
    const int lane16 = lane & 15;
    const int kgrp   = lane >> 4;

    // one j-split per XCD; 64 row-tiles sequence within the XCD
    const int jsplit = blockIdx.x & 7;
    const int rowt   = blockIdx.x >> 3;
    const int i0     = rowt * BM;
    const int jbase  = jsplit * JRANGE;

    // ---- A fragments -> registers (once) ----
    bf16x8 af[2][8];
    #pragma unroll
    for (int m = 0; m < 2; ++m) {
        const __hip_bfloat16* ap =
            A + (size_t)(i0 + wr * 32 + m * 16 + lane16) * D_DIM + kgrp * 8;
        #pragma unroll
        for (int ks = 0; ks < 8; ++ks)
            af[m][ks] = *reinterpret_cast<const bf16x8*>(ap + ks * 32);
    }

    // labels for my output rows (row = wr*32 + m*16 + kgrp*4 + r)
    int labr[2][4];
    #pragma unroll
    for (int m = 0; m < 2; ++m) {
        int4 v = *reinterpret_cast<const int4*>(labels + i0 + wr * 32 + m * 16 + kgrp * 4);
        labr[m][0] = v.x; labr[m][1] = v.y; labr[m][2] = v.z; labr[m][3] = v.w;
    }

    // ---- B staging: 32 chunks of 1KB (2 rows x 512B), 4 per wave ----
    auto stage = [&](int buf, int t) {
        const int jrow0 = jbase + t * BN;
        #pragma unroll
        for (int cc = 0; cc < 4; ++cc) {
            int c  = wid * 4 + cc;                  // chunk 0..31 (wave-uniform)
            int gr = jrow0 + c * 2 + (lane >> 5);   // global B row
            const __hip_bfloat16* src =
                B + (size_t)gr * D_DIM + (((lane & 31) ^ (gr & 15)) * 8);
            __builtin_amdgcn_global_load_lds(
                (const __attribute__((address_space(1))) void*)src,
                (__attribute__((address_space(3))) void*)((char*)&Bs[buf][0] + c * 1024),
                16, 0, 0);
        }
    };

    float allp[2][4] = {};
    float posp[2][4] = {};

    stage(0, 0);
    __syncthreads();

    for (int t = 0; t < NT; ++t) {
        const int cur = t & 1;
        if (t + 1 < NT) stage(cur ^ 1, t + 1);

        // ---- compute 128x64 logits tile: 32 MFMA per wave ----
        f32x4 acc[2][2] = {};
        #pragma unroll
        for (int ks = 0; ks < 8; ++ks) {
            bf16x8 bv[2];
            #pragma unroll
            for (int n = 0; n < 2; ++n) {
                int row   = wc * 32 + n * 16 + lane16;
                int kslot = ks * 4 + kgrp;           // 16B slot index 0..31
                bv[n] = *reinterpret_cast<const bf16x8*>(
                    (const char*)&Bs[cur][0] + row * 512 + ((kslot ^ (row & 15)) << 4));
            }
            #pragma unroll
            for (int m = 0; m < 2; ++m)
                #pragma unroll
                for (int n = 0; n < 2; ++n)
                    acc[m][n] = __builtin_amdgcn_mfma_f32_16x16x32_bf16(af[m][ks], bv[n], acc[m][n], 0, 0, 0);
        }

        // ---- epilogue: exp + mask, accumulate row sums in registers ----
        const int jc    = jbase + t * BN + wc * 32 + lane16;
        const int labc0 = labels[jc];
        const int labc1 = labels[jc + 16];
        #pragma unroll
        for (int m = 0; m < 2; ++m) {
            #pragma unroll
            for (int r = 0; r < 4; ++r) {
                float e0 = __expf(acc[m][0][r] * 2.0f);   // / TEMPERATURE
                float e1 = __expf(acc[m][1][r] * 2.0f);
                allp[m][r] += e0 + e1;
                int lr = labr[m][r];
                posp[m][r] += (lr == labc0 ? e0 : 0.0f) + (lr == labc1 ? e1 : 0.0f);
            }
        }
        __syncthreads();   // drains stage vmcnt + protects Bs[cur] reuse
    }

    // ---- final: reduce across the 16 col-lanes, one atomic per row ----
    #pragma unroll
    for (int m = 0; m < 2; ++m) {
        #pragma unroll
        for (int r = 0; r < 4; ++r) {
            float a = allp[m][r], p = posp[m][r];
            #pragma unroll
            for (int off = 1; off < 16; off <<= 1) {
                a += __shfl_xor(a, off);
                p += __shfl_xor(p, off);
            }
            if (lane16 == 0) {
                int grow = i0 + wr * 32 + m * 16 + kgrp * 4 + r;
                atomicAdd(&all_sum[grow], a);
                atomicAdd(&pos_sum[grow], p);
            }
        }
    }
}

// ---------------- kernel 3: final loss reduction ----------------------------
__global__ void loss_kernel(const float* __restrict__ pos_sum,
                            const float* __restrict__ all_sum,
                            float* __restrict__ out) {
    float acc = 0.0f;
    for (int i = threadIdx.x; i < N_ROWS; i += 1024)
        acc += logf(pos_sum[i] / all_sum[i]);
    #pragma unroll
    for (int off = 32; off; off >>= 1) acc += __shfl_xor(acc, off);
    __shared__ float red[16];
    int wv = threadIdx.x >> 6, lane = threadIdx.x & 63;
    if (lane == 0) red[wv] = acc;
    __syncthreads();
    if (threadIdx.x < 64) {
        float s = (threadIdx.x < 16) ? red[threadIdx.x] : 0.0f;
        #pragma unroll
        for (int off = 8; off; off >>= 1) s += __shfl_xor(s, off);
        if (threadIdx.x == 0) out[0] = -s / (float)N_ROWS;
    }
}

// ---------------- launch -----------------------------------------------------
extern "C" void kernel_launch(void* const* d_in, const int* in_sizes, int n_in,
                              void* d_out, int out_size, void* d_ws, size_t ws_size,
                              hipStream_t stream) {
    const float* out0   = (const float*)d_in[0];
    const float* out1   = (const float*)d_in[1];
    const int*   labels = (const int*)d_in[2];
    float*       out    = (float*)d_out;

    __hip_bfloat16* a_bf = (__hip_bfloat16*)d_ws;
    __hip_bfloat16* b_bf = a_bf + (size_t)N_ROWS * D_DIM;
    float* pos  = (float*)(b_bf + (size_t)N_ROWS * D_DIM);
    float* alls = pos + N_ROWS;

    hipMemsetAsync(pos, 0, 2 * N_ROWS * sizeof(float), stream);

    norm_cast_kernel<<<2 * N_ROWS / 4, 256, 0, stream>>>(out0, out1, a_bf, b_bf);

    fused_flash_kernel<<<JSPLIT * (N_ROWS / BM), 512, 0, stream>>>(a_bf, b_bf, labels, pos, alls);

    loss_kernel<<<1, 1024, 0, stream>>>(pos, alls, out);
}

// Round 5
// 66.302 us; speedup vs baseline: 1.1425x; 1.1425x over previous
//
#include <hip/hip_runtime.h>
#include <hip/hip_bf16.h>
#include <math.h>

#define N_ROWS 8192
#define D_DIM  256
#define BM 128
#define BN 64
#define JSPLIT 8
#define JRANGE (N_ROWS / JSPLIT)     // 1024
#define NT (JRANGE / BN)             // 16 j-steps per block

typedef __attribute__((ext_vector_type(4))) float f32x4;
typedef __attribute__((ext_vector_type(8))) short bf16x8;

// ------- kernel 1: L2-normalize rows, cast to bf16 (+ zero accumulators) ----
__global__ void norm_cast_kernel(const float* __restrict__ out0,
                                 const float* __restrict__ out1,
                                 __hip_bfloat16* __restrict__ a_bf,
                                 __hip_bfloat16* __restrict__ b_bf,
                                 float* __restrict__ zero_me) {   // pos+all, 2*N floats
    int gtid = blockIdx.x * blockDim.x + threadIdx.x;
    if (gtid < 2 * N_ROWS) zero_me[gtid] = 0.0f;

    int wave = gtid >> 6;
    int lane = threadIdx.x & 63;
    const float* src        = (wave < N_ROWS) ? out0 : out1;
    __hip_bfloat16* dst     = (wave < N_ROWS) ? a_bf : b_bf;
    int row = (wave < N_ROWS) ? wave : wave - N_ROWS;

    float4 v = *reinterpret_cast<const float4*>(src + (size_t)row * D_DIM + lane * 4);
    float ss = v.x * v.x + v.y * v.y + v.z * v.z + v.w * v.w;
    #pragma unroll
    for (int off = 32; off; off >>= 1) ss += __shfl_xor(ss, off);
    float inv = 1.0f / fmaxf(sqrtf(ss), 1e-12f);

    union { ushort4 u; __hip_bfloat16 h[4]; } o;
    o.h[0] = __float2bfloat16(v.x * inv);
    o.h[1] = __float2bfloat16(v.y * inv);
    o.h[2] = __float2bfloat16(v.z * inv);
    o.h[3] = __float2bfloat16(v.w * inv);
    *reinterpret_cast<ushort4*>(dst + (size_t)row * D_DIM + lane * 4) = o.u;
}

// ------- kernel 2: flash-style fused GEMM + exp + masked row-sums -----------
// 512 blocks = 64 row-tiles x 8 j-splits (jsplit = blockIdx&7 -> per-XCD).
// 4 waves (2 row-bands x 2 col-halves), wave-tile 64x32 (4:1 MFMA:ds_read).
// A-slice per wave in registers (full K=256, 128 VGPR). B double-buffered in
// LDS (2x32KB = 64KB -> 2 blocks/CU), staged via global_load_lds(16B) with
// 4-bit XOR swizzle: LDS[row][slot] = global[row][slot ^ (row&15)].
__global__ __launch_bounds__(256, 2)
void fused_flash_kernel(const __hip_bfloat16* __restrict__ A,
                        const __hip_bfloat16* __restrict__ B,
                        const int* __restrict__ labels,
                        float* __restrict__ pos_sum,
                        float* __restrict__ all_sum) {
    __shared__ __hip_bfloat16 Bs[2][BN * D_DIM];   // 2 x 32 KB

    const int tid    = threadIdx.x;
    const int lane   = tid & 63;
    const int wid    = tid >> 6;        // 0..3
    const int wr     = wid >> 1;        // 0..1  (64-row band)
    const int wc     = wid & 1;         // 0..1  (32-col half)
    const int lane16 = lane & 15;
    const int kgrp   = lane >> 4;

    const int jsplit = blockIdx.x & 7;
    const int rowt   = blockIdx.x >> 3;
    const int i0     = rowt * BM;
    const int jbase  = jsplit * JRANGE;

    // ---- A fragments -> registers (once) ----
    bf16x8 af[4][8];
    #pragma unroll
    for (int m = 0; m < 4; ++m) {
        const __hip_bfloat16* ap =
            A + (size_t)(i0 + wr * 64 + m * 16 + lane16) * D_DIM + kgrp * 8;
        #pragma unroll
        for (int ks = 0; ks < 8; ++ks)
            af[m][ks] = *reinterpret_cast<const bf16x8*>(ap + ks * 32);
    }

    // labels for my output rows (row = wr*64 + m*16 + kgrp*4 + r)
    int labr[4][4];
    #pragma unroll
    for (int m = 0; m < 4; ++m) {
        int4 v = *reinterpret_cast<const int4*>(labels + i0 + wr * 64 + m * 16 + kgrp * 4);
        labr[m][0] = v.x; labr[m][1] = v.y; labr[m][2] = v.z; labr[m][3] = v.w;
    }

    // ---- B staging: 32 chunks of 1KB (2 rows x 512B), 8 per wave ----
    auto stage = [&](int buf, int t) {
        const int jrow0 = jbase + t * BN;
        #pragma unroll
        for (int cc = 0; cc < 8; ++cc) {
            int c  = wid * 8 + cc;                  // chunk 0..31 (wave-uniform)
            int gr = jrow0 + c * 2 + (lane >> 5);   // global B row
            const __hip_bfloat16* src =
                B + (size_t)gr * D_DIM + (((lane & 31) ^ (gr & 15)) * 8);
            __builtin_amdgcn_global_load_lds(
                (const __attribute__((address_space(1))) void*)src,
                (__attribute__((address_space(3))) void*)((char*)&Bs[buf][0] + c * 1024),
                16, 0, 0);
        }
    };

    float allp[4][4] = {};
    float posp[4][4] = {};

    stage(0, 0);
    __syncthreads();

    for (int t = 0; t < NT; ++t) {
        const int cur = t & 1;
        if (t + 1 < NT) stage(cur ^ 1, t + 1);

        // ---- compute 128x64 logits tile: 64 MFMA per wave ----
        f32x4 acc[4][2] = {};
        __builtin_amdgcn_s_setprio(1);
        #pragma unroll
        for (int ks = 0; ks < 8; ++ks) {
            bf16x8 bv[2];
            #pragma unroll
            for (int n = 0; n < 2; ++n) {
                int row   = wc * 32 + n * 16 + lane16;
                int kslot = ks * 4 + kgrp;           // 16B slot index 0..31
                bv[n] = *reinterpret_cast<const bf16x8*>(
                    (const char*)&Bs[cur][0] + row * 512 + ((kslot ^ (row & 15)) << 4));
            }
            #pragma unroll
            for (int m = 0; m < 4; ++m)
                #pragma unroll
                for (int n = 0; n < 2; ++n)
                    acc[m][n] = __builtin_amdgcn_mfma_f32_16x16x32_bf16(af[m][ks], bv[n], acc[m][n], 0, 0, 0);
        }
        __builtin_amdgcn_s_setprio(0);

        // ---- epilogue: exp + mask, accumulate row sums in registers ----
        const int jc    = jbase + t * BN + wc * 32 + lane16;
        const int labc0 = labels[jc];
        const int labc1 = labels[jc + 16];
        #pragma unroll
        for (int m = 0; m < 4; ++m) {
            #pragma unroll
            for (int r = 0; r < 4; ++r) {
                float e0 = __expf(acc[m][0][r] * 2.0f);   // / TEMPERATURE
                float e1 = __expf(acc[m][1][r] * 2.0f);
                allp[m][r] += e0 + e1;
                int lr = labr[m][r];
                posp[m][r] += (lr == labc0 ? e0 : 0.0f) + (lr == labc1 ? e1 : 0.0f);
            }
        }
        __syncthreads();   // drains stage vmcnt + protects Bs[cur] reuse
    }

    // ---- final: reduce across the 16 col-lanes, one atomic per row ----
    #pragma unroll
    for (int m = 0; m < 4; ++m) {
        #pragma unroll
        for (int r = 0; r < 4; ++r) {
            float a = allp[m][r], p = posp[m][r];
            #pragma unroll
            for (int off = 1; off < 16; off <<= 1) {
                a += __shfl_xor(a, off);
                p += __shfl_xor(p, off);
            }
            if (lane16 == 0) {
                int grow = i0 + wr * 64 + m * 16 + kgrp * 4 + r;
                atomicAdd(&all_sum[grow], a);
                atomicAdd(&pos_sum[grow], p);
            }
        }
    }
}

// ---------------- kernel 3: final loss reduction ----------------------------
__global__ void loss_kernel(const float* __restrict__ pos_sum,
                            const float* __restrict__ all_sum,
                            float* __restrict__ out) {
    float acc = 0.0f;
    for (int i = threadIdx.x; i < N_ROWS; i += 1024)
        acc += logf(pos_sum[i] / all_sum[i]);
    #pragma unroll
    for (int off = 32; off; off >>= 1) acc += __shfl_xor(acc, off);
    __shared__ float red[16];
    int wv = threadIdx.x >> 6, lane = threadIdx.x & 63;
    if (lane == 0) red[wv] = acc;
    __syncthreads();
    if (threadIdx.x < 64) {
        float s = (threadIdx.x < 16) ? red[threadIdx.x] : 0.0f;
        #pragma unroll
        for (int off = 8; off; off >>= 1) s += __shfl_xor(s, off);
        if (threadIdx.x == 0) out[0] = -s / (float)N_ROWS;
    }
}

// ---------------- launch -----------------------------------------------------
extern "C" void kernel_launch(void* const* d_in, const int* in_sizes, int n_in,
                              void* d_out, int out_size, void* d_ws, size_t ws_size,
                              hipStream_t stream) {
    const float* out0   = (const float*)d_in[0];
    const float* out1   = (const float*)d_in[1];
    const int*   labels = (const int*)d_in[2];
    float*       out    = (float*)d_out;

    __hip_bfloat16* a_bf = (__hip_bfloat16*)d_ws;
    __hip_bfloat16* b_bf = a_bf + (size_t)N_ROWS * D_DIM;
    float* pos  = (float*)(b_bf + (size_t)N_ROWS * D_DIM);
    float* alls = pos + N_ROWS;

    norm_cast_kernel<<<2 * N_ROWS / 4, 256, 0, stream>>>(out0, out1, a_bf, b_bf, pos);

    fused_flash_kernel<<<JSPLIT * (N_ROWS / BM), 256, 0, stream>>>(a_bf, b_bf, labels, pos, alls);

    loss_kernel<<<1, 1024, 0, stream>>>(pos, alls, out);
}

// Round 7
// 61.731 us; speedup vs baseline: 1.2270x; 1.0740x over previous
//
#include <hip/hip_runtime.h>
#include <hip/hip_bf16.h>
#include <math.h>

#define N_ROWS 8192
#define D_DIM  256
#define BM 128
#define BN 64
#define JSPLIT 8
#define JRANGE (N_ROWS / JSPLIT)     // 1024
#define NT (JRANGE / BN)             // 16 j-steps per block

typedef __attribute__((ext_vector_type(4))) float f32x4;
typedef __attribute__((ext_vector_type(8))) short bf16x8;

// ------- kernel 1: L2-normalize rows, cast to bf16 (+ zero accumulators) ----
__global__ void norm_cast_kernel(const float* __restrict__ out0,
                                 const float* __restrict__ out1,
                                 __hip_bfloat16* __restrict__ a_bf,
                                 __hip_bfloat16* __restrict__ b_bf,
                                 float* __restrict__ zero_me) {   // pos+all, 2*N floats
    int gtid = blockIdx.x * blockDim.x + threadIdx.x;
    if (gtid < 2 * N_ROWS) zero_me[gtid] = 0.0f;

    int wave = gtid >> 6;
    int lane = threadIdx.x & 63;
    const float* src        = (wave < N_ROWS) ? out0 : out1;
    __hip_bfloat16* dst     = (wave < N_ROWS) ? a_bf : b_bf;
    int row = (wave < N_ROWS) ? wave : wave - N_ROWS;

    float4 v = *reinterpret_cast<const float4*>(src + (size_t)row * D_DIM + lane * 4);
    float ss = v.x * v.x + v.y * v.y + v.z * v.z + v.w * v.w;
    #pragma unroll
    for (int off = 32; off; off >>= 1) ss += __shfl_xor(ss, off);
    float inv = 1.0f / fmaxf(sqrtf(ss), 1e-12f);

    union { ushort4 u; __hip_bfloat16 h[4]; } o;
    o.h[0] = __float2bfloat16(v.x * inv);
    o.h[1] = __float2bfloat16(v.y * inv);
    o.h[2] = __float2bfloat16(v.z * inv);
    o.h[3] = __float2bfloat16(v.w * inv);
    *reinterpret_cast<ushort4*>(dst + (size_t)row * D_DIM + lane * 4) = o.u;
}

// ------- kernel 2: flash-style fused GEMM + exp + masked row-sums -----------
// 512 blocks = 64 row-tiles x 8 j-splits (jsplit = blockIdx&7 -> per-XCD).
// 4 waves (2 row-bands x 2 col-halves), wave-tile 64x32. A-slice per wave
// PINNED in registers via asm (128 VGPR — prevents compiler rematerialization,
// the r3-r5 killer). B double-buffered in LDS (2x32KB -> 2 blocks/CU), staged
// via global_load_lds(16B) with 4-bit XOR swizzle.
__global__ __launch_bounds__(256, 2)
void fused_flash_kernel(const __hip_bfloat16* __restrict__ A,
                        const __hip_bfloat16* __restrict__ B,
                        const int* __restrict__ labels,
                        float* __restrict__ pos_sum,
                        float* __restrict__ all_sum) {
    __shared__ __hip_bfloat16 Bs[2][BN * D_DIM];   // 2 x 32 KB

    const int tid    = threadIdx.x;
    const int lane   = tid & 63;
    const int wid    = tid >> 6;        // 0..3
    const int wr     = wid >> 1;        // 0..1  (64-row band)
    const int wc     = wid & 1;         // 0..1  (32-col half)
    const int lane16 = lane & 15;
    const int kgrp   = lane >> 4;

    const int jsplit = blockIdx.x & 7;
    const int rowt   = blockIdx.x >> 3;
    const int i0     = rowt * BM;
    const int jbase  = jsplit * JRANGE;

    // ---- A fragments -> registers (once), PINNED against rematerialization ----
    bf16x8 af[4][8];
    #pragma unroll
    for (int m = 0; m < 4; ++m) {
        const __hip_bfloat16* ap =
            A + (size_t)(i0 + wr * 64 + m * 16 + lane16) * D_DIM + kgrp * 8;
        #pragma unroll
        for (int ks = 0; ks < 8; ++ks)
            af[m][ks] = *reinterpret_cast<const bf16x8*>(ap + ks * 32);
    }
    #pragma unroll
    for (int m = 0; m < 4; ++m)
        #pragma unroll
        for (int ks = 0; ks < 8; ++ks)
            asm volatile("" : "+v"(af[m][ks]));

    // labels for my output rows (row = wr*64 + m*16 + kgrp*4 + r), pinned
    int labr[4][4];
    #pragma unroll
    for (int m = 0; m < 4; ++m) {
        int4 v = *reinterpret_cast<const int4*>(labels + i0 + wr * 64 + m * 16 + kgrp * 4);
        labr[m][0] = v.x; labr[m][1] = v.y; labr[m][2] = v.z; labr[m][3] = v.w;
        #pragma unroll
        for (int r = 0; r < 4; ++r)
            asm volatile("" : "+v"(labr[m][r]));
    }

    // ---- B staging: 32 chunks of 1KB (2 rows x 512B), 8 per wave ----
    auto stage = [&](int buf, int t) {
        const int jrow0 = jbase + t * BN;
        #pragma unroll
        for (int cc = 0; cc < 8; ++cc) {
            int c  = wid * 8 + cc;                  // chunk 0..31 (wave-uniform)
            int gr = jrow0 + c * 2 + (lane >> 5);   // global B row
            const __hip_bfloat16* src =
                B + (size_t)gr * D_DIM + (((lane & 31) ^ (gr & 15)) * 8);
            __builtin_amdgcn_global_load_lds(
                (const __attribute__((address_space(1))) void*)src,
                (__attribute__((address_space(3))) void*)((char*)&Bs[buf][0] + c * 1024),
                16, 0, 0);
        }
    };

    float allp[4][4] = {};
    float posp[4][4] = {};

    stage(0, 0);
    __syncthreads();

    for (int t = 0; t < NT; ++t) {
        const int cur = t & 1;
        if (t + 1 < NT) stage(cur ^ 1, t + 1);

        // issue column-label loads early (hide under MFMA)
        const int jc    = jbase + t * BN + wc * 32 + lane16;
        const int labc0 = labels[jc];
        const int labc1 = labels[jc + 16];

        // ---- compute 128x64 logits tile: 64 MFMA per wave ----
        f32x4 acc[4][2] = {};
        __builtin_amdgcn_s_setprio(1);
        #pragma unroll
        for (int ks = 0; ks < 8; ++ks) {
            bf16x8 bv[2];
            #pragma unroll
            for (int n = 0; n < 2; ++n) {
                int row   = wc * 32 + n * 16 + lane16;
                int kslot = ks * 4 + kgrp;           // 16B slot index 0..31
                bv[n] = *reinterpret_cast<const bf16x8*>(
                    (const char*)&Bs[cur][0] + row * 512 + ((kslot ^ (row & 15)) << 4));
            }
            #pragma unroll
            for (int m = 0; m < 4; ++m)
                #pragma unroll
                for (int n = 0; n < 2; ++n)
                    acc[m][n] = __builtin_amdgcn_mfma_f32_16x16x32_bf16(af[m][ks], bv[n], acc[m][n], 0, 0, 0);
        }
        __builtin_amdgcn_s_setprio(0);

        // all waves done reading Bs[cur]; stage(t+1) already issued and will be
        // vmcnt-drained here -> next iteration's reads are safe. Epilogue below
        // overlaps with other waves' staging/ds_reads.
        __syncthreads();

        // ---- epilogue: exp + mask, accumulate row sums in registers ----
        #pragma unroll
        for (int m = 0; m < 4; ++m) {
            #pragma unroll
            for (int r = 0; r < 4; ++r) {
                float e0 = __expf(acc[m][0][r] * 2.0f);   // / TEMPERATURE
                float e1 = __expf(acc[m][1][r] * 2.0f);
                allp[m][r] += e0 + e1;
                int lr = labr[m][r];
                posp[m][r] += (lr == labc0 ? e0 : 0.0f) + (lr == labc1 ? e1 : 0.0f);
            }
        }
    }

    // ---- final: reduce across the 16 col-lanes, one atomic per row ----
    #pragma unroll
    for (int m = 0; m < 4; ++m) {
        #pragma unroll
        for (int r = 0; r < 4; ++r) {
            float a = allp[m][r], p = posp[m][r];
            #pragma unroll
            for (int off = 1; off < 16; off <<= 1) {
                a += __shfl_xor(a, off);
                p += __shfl_xor(p, off);
            }
            if (lane16 == 0) {
                int grow = i0 + wr * 64 + m * 16 + kgrp * 4 + r;
                atomicAdd(&all_sum[grow], a);
                atomicAdd(&pos_sum[grow], p);
            }
        }
    }
}

// ---------------- kernel 3: final loss reduction ----------------------------
__global__ void loss_kernel(const float* __restrict__ pos_sum,
                            const float* __restrict__ all_sum,
                            float* __restrict__ out) {
    float acc = 0.0f;
    for (int i = threadIdx.x; i < N_ROWS; i += 1024)
        acc += logf(pos_sum[i] / all_sum[i]);
    #pragma unroll
    for (int off = 32; off; off >>= 1) acc += __shfl_xor(acc, off);
    __shared__ float red[16];
    int wv = threadIdx.x >> 6, lane = threadIdx.x & 63;
    if (lane == 0) red[wv] = acc;
    __syncthreads();
    if (threadIdx.x < 64) {
        float s = (threadIdx.x < 16) ? red[threadIdx.x] : 0.0f;
        #pragma unroll
        for (int off = 8; off; off >>= 1) s += __shfl_xor(s, off);
        if (threadIdx.x == 0) out[0] = -s / (float)N_ROWS;
    }
}

// ---------------- launch -----------------------------------------------------
extern "C" void kernel_launch(void* const* d_in, const int* in_sizes, int n_in,
                              void* d_out, int out_size, void* d_ws, size_t ws_size,
                              hipStream_t stream) {
    const float* out0   = (const float*)d_in[0];
    const float* out1   = (const float*)d_in[1];
    const int*   labels = (const int*)d_in[2];
    float*       out    = (float*)d_out;

    __hip_bfloat16* a_bf = (__hip_bfloat16*)d_ws;
    __hip_bfloat16* b_bf = a_bf + (size_t)N_ROWS * D_DIM;
    float* pos  = (float*)(b_bf + (size_t)N_ROWS * D_DIM);
    float* alls = pos + N_ROWS;

    norm_cast_kernel<<<2 * N_ROWS / 4, 256, 0, stream>>>(out0, out1, a_bf, b_bf, pos);

    fused_flash_kernel<<<JSPLIT * (N_ROWS / BM), 256, 0, stream>>>(a_bf, b_bf, labels, pos, alls);

    loss_kernel<<<1, 1024, 0, stream>>>(pos, alls, out);
}